// Round 1
// baseline (907.070 us; speedup 1.0000x reference)
//
#include <hip/hip_runtime.h>
#include <math.h>

// Problem: MultiHeadAttention  B=4, T=2048, D=512, H=8, DH=64, fp32 in/out.
// Pipeline: QKV proj GEMMs -> flash attention (key padding mask) -> O proj.
// All fp32 (CDNA4 has no fp32 MFMA; vector-ALU GEMM). bf16/MFMA deferred
// until we know the validation tolerance headroom.

#define TB 2048
#define DD 512
#define NH 8
#define DH 64

// ---------------------------------------------------------------------------
// Mask canonicalization. padding_mask is jax bool [B,1,1,T] = 8192 elems; the
// harness may hand it to us as int8 (raw bool), int32, or float32. Detect by
// byte-phase signature over the first 8192 bytes (safe under all layouts):
//   bool   : ~90% of ALL bytes nonzero
//   int32  : only bytes at i%4==0 nonzero (values 0/1)
//   float32: 1.0f = 00 00 80 3f -> bytes at i%4==2,3 nonzero, i%4==1 zero
__global__ void mask_detect_kernel(const unsigned char* __restrict__ m,
                                   int* __restrict__ mode) {
  __shared__ int c1, c2;
  if (threadIdx.x == 0) { c1 = 0; c2 = 0; }
  __syncthreads();
  int l1 = 0, l2 = 0;
  for (int i = threadIdx.x; i < 8192; i += blockDim.x) {
    int ph = i & 3;
    unsigned char v = m[i];
    if (ph == 1 && v) l1++;
    if (ph == 2 && v) l2++;
  }
  if (l1) atomicAdd(&c1, l1);
  if (l2) atomicAdd(&c2, l2);
  __syncthreads();
  if (threadIdx.x == 0) {
    // c1>0 -> raw bool bytes; else c2>0 -> float32; else int32
    *mode = (c1 > 0) ? 0 : ((c2 > 0) ? 1 : 2);
  }
}

__global__ void mask_build_kernel(const void* __restrict__ m,
                                  const int* __restrict__ mode,
                                  int* __restrict__ out) {
  int i = blockIdx.x * blockDim.x + threadIdx.x;  // 8192 threads total
  int md = *mode;
  int v;
  if (md == 0)      v = ((const unsigned char*)m)[i] != 0;
  else if (md == 1) v = ((const float*)m)[i] != 0.0f;
  else              v = ((const int*)m)[i] != 0;
  out[i] = v;
}

// ---------------------------------------------------------------------------
// fp32 GEMM: Y = X @ W + b.  M=8192, N=512, K=512. 128x128 tile, BK=16,
// 256 threads, 8x8 micro-tile (split 4+4 so LDS float4 reads are 2-way max).
// MODE 0: scatter to head layout [B,H,T,DH]; MODE 1: flat [M,N] (d_out).
template <int MODE>
__global__ __launch_bounds__(256) void proj_gemm_kernel(
    const float* __restrict__ A, const float* __restrict__ W,
    const float* __restrict__ bias, float* __restrict__ Y) {
  __shared__ float As[16][128];  // As[k][m]
  __shared__ float Bs[16][128];  // Bs[k][n]

  const int tid = threadIdx.x;
  const int tx = tid & 15, ty = tid >> 4;
  const int bm = blockIdx.y << 7;  // 0..8064
  const int bn = blockIdx.x << 7;  // 0..384

  float acc[8][8];
#pragma unroll
  for (int i = 0; i < 8; ++i)
#pragma unroll
    for (int j = 0; j < 8; ++j) acc[i][j] = 0.f;

  for (int k0 = 0; k0 < DD; k0 += 16) {
    float4 av[2], bv[2];
#pragma unroll
    for (int l = 0; l < 2; ++l) {
      int f = tid + l * 256;  // 0..511 float4 units
      av[l] = *(const float4*)&A[(size_t)(bm + (f >> 2)) * DD + k0 + ((f & 3) << 2)];
      bv[l] = *(const float4*)&W[(size_t)(k0 + (f >> 5)) * DD + bn + ((f & 31) << 2)];
    }
    __syncthreads();
#pragma unroll
    for (int l = 0; l < 2; ++l) {
      int f = tid + l * 256;
      int r = f >> 2, c4 = (f & 3) << 2;
      As[c4 + 0][r] = av[l].x;
      As[c4 + 1][r] = av[l].y;
      As[c4 + 2][r] = av[l].z;
      As[c4 + 3][r] = av[l].w;
      *(float4*)&Bs[f >> 5][(f & 31) << 2] = bv[l];
    }
    __syncthreads();
#pragma unroll 8
    for (int kk = 0; kk < 16; ++kk) {
      float4 a0 = *(const float4*)&As[kk][ty << 2];
      float4 a1 = *(const float4*)&As[kk][(ty << 2) + 64];
      float4 b0 = *(const float4*)&Bs[kk][tx << 2];
      float4 b1 = *(const float4*)&Bs[kk][(tx << 2) + 64];
      float ar[8] = {a0.x, a0.y, a0.z, a0.w, a1.x, a1.y, a1.z, a1.w};
      float br[8] = {b0.x, b0.y, b0.z, b0.w, b1.x, b1.y, b1.z, b1.w};
#pragma unroll
      for (int i = 0; i < 8; ++i)
#pragma unroll
        for (int j = 0; j < 8; ++j) acc[i][j] += ar[i] * br[j];
    }
    __syncthreads();
  }

  // epilogue
#pragma unroll
  for (int rg = 0; rg < 2; ++rg) {
#pragma unroll
    for (int i = 0; i < 4; ++i) {
      int row = bm + rg * 64 + (ty << 2) + i;
#pragma unroll
      for (int cg = 0; cg < 2; ++cg) {
        int col = bn + cg * 64 + (tx << 2);
        float4 bb = *(const float4*)&bias[col];
        float4 o;
        o.x = acc[rg * 4 + i][cg * 4 + 0] + bb.x;
        o.y = acc[rg * 4 + i][cg * 4 + 1] + bb.y;
        o.z = acc[rg * 4 + i][cg * 4 + 2] + bb.z;
        o.w = acc[rg * 4 + i][cg * 4 + 3] + bb.w;
        if (MODE == 0) {
          // head layout: Y[b][h][t][dh]; col block of 64 == one head exactly
          int b = row >> 11, t = row & (TB - 1);
          int h = col >> 6, dh = col & (DH - 1);
          *(float4*)&Y[((((size_t)b * NH + h) * TB) + t) * DH + dh] = o;
        } else {
          *(float4*)&Y[(size_t)row * DD + col] = o;
        }
      }
    }
  }
}

// ---------------------------------------------------------------------------
// Flash attention: per block one (b,h) and 64 q rows; iterate 32 K/V tiles of
// 64 keys. 256 threads, 4x4 micro. Online softmax in registers; row stats
// replicated across the 16 lanes of each row group via shfl_xor.
// LDS: Qs[d][i] 16KB, KP (K^T / P^T union, stride 68) 17KB, Vs 16KB ~ 50KB.
__global__ __launch_bounds__(256) void attn_kernel(
    const float* __restrict__ Qh, const float* __restrict__ Kh,
    const float* __restrict__ Vh, const int* __restrict__ maskc,
    float* __restrict__ Xc) {
  __shared__ float Qs[64][64];   // Qs[d][i] = Q[q0+i][d]
  __shared__ float KP[64 * 68];  // phase1: K^T  KP[d*68+j] = K[kt+j][d]
                                 // phase2: P^T  KP[k*68+i] = P[i][k]
  __shared__ float Vs[64][64];   // Vs[k][dh]
  __shared__ int mk[64];

  const int tid = threadIdx.x;
  const int tx = tid & 15, ty = tid >> 4;
  const int bh = blockIdx.y;  // 0..31
  const int b = bh >> 3, h = bh & 7;
  const int q0 = blockIdx.x << 6;

  const float* Qbase = Qh + ((size_t)bh * TB + q0) * DH;
  const float* Kbase = Kh + (size_t)bh * TB * DH;
  const float* Vbase = Vh + (size_t)bh * TB * DH;

  // stage Q tile transposed
#pragma unroll
  for (int l = 0; l < 4; ++l) {
    int f = tid + l * 256;  // 0..1023 float4 units (64 rows x 16 f4/row)
    int r = f >> 4, c4 = (f & 15) << 2;
    float4 qv = *(const float4*)&Qbase[r * DH + c4];
    Qs[c4 + 0][r] = qv.x;
    Qs[c4 + 1][r] = qv.y;
    Qs[c4 + 2][r] = qv.z;
    Qs[c4 + 3][r] = qv.w;
  }

  float acc[4][4];
  float mrow[4], lrow[4];
#pragma unroll
  for (int i = 0; i < 4; ++i) {
    mrow[i] = -INFINITY;
    lrow[i] = 0.f;
#pragma unroll
    for (int j = 0; j < 4; ++j) acc[i][j] = 0.f;
  }
  const float scale = 0.125f;  // 1/sqrt(64)

  for (int kt = 0; kt < TB; kt += 64) {
    __syncthreads();  // (A) prior PV readers of KP/Vs done
    // stage K^T, V, mask tile
    const float* Kt = Kbase + kt * DH;
    const float* Vt = Vbase + kt * DH;
#pragma unroll
    for (int l = 0; l < 4; ++l) {
      int f = tid + l * 256;
      int r = f >> 4, c4 = (f & 15) << 2;
      float4 kv = *(const float4*)&Kt[r * DH + c4];
      KP[(c4 + 0) * 68 + r] = kv.x;
      KP[(c4 + 1) * 68 + r] = kv.y;
      KP[(c4 + 2) * 68 + r] = kv.z;
      KP[(c4 + 3) * 68 + r] = kv.w;
      *(float4*)&Vs[r][c4] = *(const float4*)&Vt[r * DH + c4];
    }
    if (tid < 64) mk[tid] = maskc[b * TB + kt + tid];
    __syncthreads();  // (B)

    // S = Q K^T (4x4 per thread)
    float s[4][4];
#pragma unroll
    for (int i = 0; i < 4; ++i)
#pragma unroll
      for (int j = 0; j < 4; ++j) s[i][j] = 0.f;
#pragma unroll 8
    for (int d = 0; d < DH; ++d) {
      float4 a = *(const float4*)&Qs[d][ty << 2];
      float4 bb = *(const float4*)&KP[d * 68 + (tx << 2)];
      float ar[4] = {a.x, a.y, a.z, a.w};
      float br[4] = {bb.x, bb.y, bb.z, bb.w};
#pragma unroll
      for (int i = 0; i < 4; ++i)
#pragma unroll
        for (int j = 0; j < 4; ++j) s[i][j] += ar[i] * br[j];
    }

    // mask + scale
#pragma unroll
    for (int j = 0; j < 4; ++j) {
      int keep = mk[(tx << 2) + j];
#pragma unroll
      for (int i = 0; i < 4; ++i)
        s[i][j] = keep ? s[i][j] * scale : -INFINITY;
    }

    // online softmax per row (rows shared by the 16 lanes of a ty-group)
    float pv[4][4];
#pragma unroll
    for (int i = 0; i < 4; ++i) {
      float tmax = fmaxf(fmaxf(s[i][0], s[i][1]), fmaxf(s[i][2], s[i][3]));
#pragma unroll
      for (int off = 1; off < 16; off <<= 1)
        tmax = fmaxf(tmax, __shfl_xor(tmax, off, 64));
      float newm = fmaxf(mrow[i], tmax);
      float alpha, rsum;
      if (newm == -INFINITY) {  // everything masked so far
        alpha = 1.f;
        rsum = 0.f;
#pragma unroll
        for (int j = 0; j < 4; ++j) pv[i][j] = 0.f;
      } else {
        alpha = __expf(mrow[i] - newm);  // exp(-inf)=0 handles first tile
        rsum = 0.f;
#pragma unroll
        for (int j = 0; j < 4; ++j) {
          pv[i][j] = __expf(s[i][j] - newm);  // masked: exp(-inf)=0
          rsum += pv[i][j];
        }
#pragma unroll
        for (int off = 1; off < 16; off <<= 1)
          rsum += __shfl_xor(rsum, off, 64);
      }
      mrow[i] = newm;
      lrow[i] = lrow[i] * alpha + rsum;
#pragma unroll
      for (int j = 0; j < 4; ++j) acc[i][j] *= alpha;
    }

    __syncthreads();  // (B2) all K^T reads done; KP becomes P^T
#pragma unroll
    for (int jj = 0; jj < 4; ++jj) {
      *(float4*)&KP[((tx << 2) + jj) * 68 + (ty << 2)] =
          make_float4(pv[0][jj], pv[1][jj], pv[2][jj], pv[3][jj]);
    }
    __syncthreads();  // (C)

    // O += P V
#pragma unroll 8
    for (int k = 0; k < 64; ++k) {
      float4 a = *(const float4*)&KP[k * 68 + (ty << 2)];
      float4 bb = *(const float4*)&Vs[k][tx << 2];
      float ar[4] = {a.x, a.y, a.z, a.w};
      float br[4] = {bb.x, bb.y, bb.z, bb.w};
#pragma unroll
      for (int i = 0; i < 4; ++i)
#pragma unroll
        for (int j = 0; j < 4; ++j) acc[i][j] += ar[i] * br[j];
    }
  }

  // epilogue: divide by l (0 if fully masked) and write [B,T,D] context
#pragma unroll
  for (int i = 0; i < 4; ++i) {
    float inv = (lrow[i] > 0.f) ? 1.f / lrow[i] : 0.f;
    int t = q0 + (ty << 2) + i;
    float4 o = make_float4(acc[i][0] * inv, acc[i][1] * inv, acc[i][2] * inv,
                           acc[i][3] * inv);
    *(float4*)&Xc[((size_t)b * TB + t) * DD + h * DH + (tx << 2)] = o;
  }
}

// ---------------------------------------------------------------------------
extern "C" void kernel_launch(void* const* d_in, const int* in_sizes, int n_in,
                              void* d_out, int out_size, void* d_ws,
                              size_t ws_size, hipStream_t stream) {
  (void)in_sizes; (void)n_in; (void)out_size; (void)ws_size;
  const float* q = (const float*)d_in[0];
  const float* k = (const float*)d_in[1];
  const float* v = (const float*)d_in[2];
  const void* pm = d_in[3];
  const float* Wq = (const float*)d_in[4];
  const float* bq = (const float*)d_in[5];
  const float* Wk = (const float*)d_in[6];
  const float* bk = (const float*)d_in[7];
  const float* Wv = (const float*)d_in[8];
  const float* bv = (const float*)d_in[9];
  const float* Wo = (const float*)d_in[10];
  const float* bo = (const float*)d_in[11];

  char* ws = (char*)d_ws;
  const size_t SZH = (size_t)4 * NH * TB * DH * sizeof(float);  // 16 MiB
  float* Qh = (float*)(ws);
  float* Kh = (float*)(ws + SZH);
  float* Vh = (float*)(ws + 2 * SZH);
  float* Xc = (float*)(ws + 3 * SZH);
  int* maskc = (int*)(ws + 4 * SZH);
  int* mode = (int*)(ws + 4 * SZH + 8192 * sizeof(int));

  mask_detect_kernel<<<1, 256, 0, stream>>>((const unsigned char*)pm, mode);
  mask_build_kernel<<<32, 256, 0, stream>>>(pm, mode, maskc);

  dim3 gemm_grid(DD / 128, (4 * TB) / 128);  // (4, 64)
  proj_gemm_kernel<0><<<gemm_grid, 256, 0, stream>>>(q, Wq, bq, Qh);
  proj_gemm_kernel<0><<<gemm_grid, 256, 0, stream>>>(k, Wk, bk, Kh);
  proj_gemm_kernel<0><<<gemm_grid, 256, 0, stream>>>(v, Wv, bv, Vh);

  attn_kernel<<<dim3(TB / 64, 4 * NH), 256, 0, stream>>>(Qh, Kh, Vh, maskc, Xc);

  proj_gemm_kernel<1><<<gemm_grid, 256, 0, stream>>>(Xc, Wo, bo, (float*)d_out);
}

// Round 2
// 704.609 us; speedup vs baseline: 1.2873x; 1.2873x over previous
//
#include <hip/hip_runtime.h>
#include <hip/hip_bf16.h>
#include <math.h>

// MultiHeadAttention  B=4, T=2048, D=512, H=8, DH=64, fp32 in/out.
// R2: attention on bf16 MFMA (16x16x32). Projections stay fp32 VALU but
// emit bf16 Q (pre-scaled by 0.125), bf16 K, bf16 V^T [B,H,DH,T].

#define TB 2048
#define DD 512
#define NH 8
#define DH 64

typedef short bf16x8 __attribute__((ext_vector_type(8)));
typedef float f32x4 __attribute__((ext_vector_type(4)));

static __device__ __forceinline__ ushort f2bf(float x) {
  __hip_bfloat16 h = __float2bfloat16(x);
  return *reinterpret_cast<ushort*>(&h);
}

// ---------------------------------------------------------------------------
// Mask canonicalization (unchanged from R1; detection verified working).
__global__ void mask_detect_kernel(const unsigned char* __restrict__ m,
                                   int* __restrict__ mode) {
  __shared__ int c1, c2;
  if (threadIdx.x == 0) { c1 = 0; c2 = 0; }
  __syncthreads();
  int l1 = 0, l2 = 0;
  for (int i = threadIdx.x; i < 8192; i += blockDim.x) {
    int ph = i & 3;
    unsigned char v = m[i];
    if (ph == 1 && v) l1++;
    if (ph == 2 && v) l2++;
  }
  if (l1) atomicAdd(&c1, l1);
  if (l2) atomicAdd(&c2, l2);
  __syncthreads();
  if (threadIdx.x == 0) *mode = (c1 > 0) ? 0 : ((c2 > 0) ? 1 : 2);
}

__global__ void mask_build_kernel(const void* __restrict__ m,
                                  const int* __restrict__ mode,
                                  int* __restrict__ out) {
  int i = blockIdx.x * blockDim.x + threadIdx.x;
  int md = *mode;
  int v;
  if (md == 0)      v = ((const unsigned char*)m)[i] != 0;
  else if (md == 1) v = ((const float*)m)[i] != 0.0f;
  else              v = ((const int*)m)[i] != 0;
  out[i] = v;
}

// ---------------------------------------------------------------------------
// fp32 GEMM Y = (X @ W + b) * scale.  M=8192,N=512,K=512. 128x128 tile.
// MODE 0: bf16 head layout [B,H,T,DH]; MODE 1: f32 flat [M,N];
// MODE 2: bf16 transposed head layout [B,H,DH,T] (for V).
template <int MODE>
__global__ __launch_bounds__(256) void proj_gemm_kernel(
    const float* __restrict__ A, const float* __restrict__ W,
    const float* __restrict__ bias, void* __restrict__ Yv, float scale) {
  __shared__ float As[16][128];
  __shared__ float Bs[16][128];

  const int tid = threadIdx.x;
  const int tx = tid & 15, ty = tid >> 4;
  const int bm = blockIdx.y << 7;
  const int bn = blockIdx.x << 7;

  float acc[8][8];
#pragma unroll
  for (int i = 0; i < 8; ++i)
#pragma unroll
    for (int j = 0; j < 8; ++j) acc[i][j] = 0.f;

  for (int k0 = 0; k0 < DD; k0 += 16) {
    float4 av[2], bv[2];
#pragma unroll
    for (int l = 0; l < 2; ++l) {
      int f = tid + l * 256;
      av[l] = *(const float4*)&A[(size_t)(bm + (f >> 2)) * DD + k0 + ((f & 3) << 2)];
      bv[l] = *(const float4*)&W[(size_t)(k0 + (f >> 5)) * DD + bn + ((f & 31) << 2)];
    }
    __syncthreads();
#pragma unroll
    for (int l = 0; l < 2; ++l) {
      int f = tid + l * 256;
      int r = f >> 2, c4 = (f & 3) << 2;
      As[c4 + 0][r] = av[l].x;
      As[c4 + 1][r] = av[l].y;
      As[c4 + 2][r] = av[l].z;
      As[c4 + 3][r] = av[l].w;
      *(float4*)&Bs[f >> 5][(f & 31) << 2] = bv[l];
    }
    __syncthreads();
#pragma unroll 8
    for (int kk = 0; kk < 16; ++kk) {
      float4 a0 = *(const float4*)&As[kk][ty << 2];
      float4 a1 = *(const float4*)&As[kk][(ty << 2) + 64];
      float4 b0 = *(const float4*)&Bs[kk][tx << 2];
      float4 b1 = *(const float4*)&Bs[kk][(tx << 2) + 64];
      float ar[8] = {a0.x, a0.y, a0.z, a0.w, a1.x, a1.y, a1.z, a1.w};
      float br[8] = {b0.x, b0.y, b0.z, b0.w, b1.x, b1.y, b1.z, b1.w};
#pragma unroll
      for (int i = 0; i < 8; ++i)
#pragma unroll
        for (int j = 0; j < 8; ++j) acc[i][j] += ar[i] * br[j];
    }
    __syncthreads();
  }

  float* Yf = (float*)Yv;
  ushort* Yb = (ushort*)Yv;

  if (MODE == 1) {
#pragma unroll
    for (int rg = 0; rg < 2; ++rg)
#pragma unroll
      for (int i = 0; i < 4; ++i) {
        int row = bm + rg * 64 + (ty << 2) + i;
#pragma unroll
        for (int cg = 0; cg < 2; ++cg) {
          int col = bn + cg * 64 + (tx << 2);
          float4 bb = *(const float4*)&bias[col];
          float4 o;
          o.x = (acc[rg * 4 + i][cg * 4 + 0] + bb.x) * scale;
          o.y = (acc[rg * 4 + i][cg * 4 + 1] + bb.y) * scale;
          o.z = (acc[rg * 4 + i][cg * 4 + 2] + bb.z) * scale;
          o.w = (acc[rg * 4 + i][cg * 4 + 3] + bb.w) * scale;
          *(float4*)&Yf[(size_t)row * DD + col] = o;
        }
      }
  } else if (MODE == 0) {
#pragma unroll
    for (int rg = 0; rg < 2; ++rg)
#pragma unroll
      for (int i = 0; i < 4; ++i) {
        int row = bm + rg * 64 + (ty << 2) + i;
        int b = row >> 11, t = row & (TB - 1);
#pragma unroll
        for (int cg = 0; cg < 2; ++cg) {
          int col = bn + cg * 64 + (tx << 2);
          float4 bb = *(const float4*)&bias[col];
          int h = col >> 6, dh = col & (DH - 1);
          ushort4 o;
          o.x = f2bf((acc[rg * 4 + i][cg * 4 + 0] + bb.x) * scale);
          o.y = f2bf((acc[rg * 4 + i][cg * 4 + 1] + bb.y) * scale);
          o.z = f2bf((acc[rg * 4 + i][cg * 4 + 2] + bb.z) * scale);
          o.w = f2bf((acc[rg * 4 + i][cg * 4 + 3] + bb.w) * scale);
          *(ushort4*)&Yb[((((size_t)b * NH + h) * TB) + t) * DH + dh] = o;
        }
      }
  } else {  // MODE 2: transposed [B,H,DH,T]
#pragma unroll
    for (int rg = 0; rg < 2; ++rg) {
      int t0 = bm + rg * 64 + (ty << 2);
      int b = t0 >> 11, tl = t0 & (TB - 1);
#pragma unroll
      for (int cg = 0; cg < 2; ++cg) {
        int col0 = bn + cg * 64 + (tx << 2);
        float4 bb = *(const float4*)&bias[col0];
        float ba[4] = {bb.x, bb.y, bb.z, bb.w};
#pragma unroll
        for (int jj = 0; jj < 4; ++jj) {
          int col = col0 + jj;
          int h = col >> 6, dh = col & (DH - 1);
          ushort4 o;
          o.x = f2bf((acc[rg * 4 + 0][cg * 4 + jj] + ba[jj]) * scale);
          o.y = f2bf((acc[rg * 4 + 1][cg * 4 + jj] + ba[jj]) * scale);
          o.z = f2bf((acc[rg * 4 + 2][cg * 4 + jj] + ba[jj]) * scale);
          o.w = f2bf((acc[rg * 4 + 3][cg * 4 + jj] + ba[jj]) * scale);
          *(ushort4*)&Yb[(((size_t)b * NH + h) * DH + dh) * TB + tl] = o;
        }
      }
    }
  }
}

// ---------------------------------------------------------------------------
// bf16 MFMA flash attention. Grid: 1024 blocks (XCD-swizzled so each bh's 32
// blocks share one XCD's L2), 256 threads = 4 independent waves (no barriers).
// Wave w: 16 q-rows. Per 64-key tile: QK^T = 8 mfma (K frags from global),
// wave-parallel online softmax in C-layout, P via per-wave padded LDS to
// A-layout, PV = 8 mfma (V^T frags from global, contiguous).
__global__ __launch_bounds__(256) void attn_mfma_kernel(
    const ushort* __restrict__ Qh,  // [BH][T][DH], pre-scaled by 0.125
    const ushort* __restrict__ Kh,  // [BH][T][DH]
    const ushort* __restrict__ Vt,  // [BH][DH][T]
    const int* __restrict__ maskc,  // [B][T]
    float* __restrict__ Xc) {       // [B][T][D]
  __shared__ __align__(16) ushort Plds[4][16][72];

  const int tid = threadIdx.x;
  const int w = tid >> 6, lane = tid & 63;
  const int lhi = lane >> 4, llo = lane & 15;

  const int bid = blockIdx.x;
  const int j = bid >> 3;
  const int bh = (bid & 7) + ((j >> 5) << 3);  // same-bh blocks -> same XCD
  const int qt = j & 31;
  const int b = bh >> 3, h = bh & 7;
  const int q0 = qt << 6;

  const ushort* Qb = Qh + ((size_t)bh * TB + q0 + w * 16) * DH;
  const ushort* Kb = Kh + (size_t)bh * TB * DH;
  const ushort* Vb = Vt + (size_t)bh * DH * TB;
  const int* mb = maskc + b * TB;
  ushort* pl = &Plds[w][0][0];

  // Q A-frags: row = llo, k = kc*32 + lhi*8 + [0..7]
  bf16x8 qa0 = *(const bf16x8*)&Qb[llo * DH + lhi * 8];
  bf16x8 qa1 = *(const bf16x8*)&Qb[llo * DH + 32 + lhi * 8];

  f32x4 oacc[4];
  float mrow[4], lrow[4];
#pragma unroll
  for (int i = 0; i < 4; ++i) {
    oacc[i] = (f32x4){0.f, 0.f, 0.f, 0.f};
    mrow[i] = -INFINITY;
    lrow[i] = 0.f;
  }

  for (int kt = 0; kt < TB; kt += 64) {
    // ---- S = Q K^T ----
    f32x4 s[4];
#pragma unroll
    for (int nt = 0; nt < 4; ++nt) s[nt] = (f32x4){0.f, 0.f, 0.f, 0.f};
#pragma unroll
    for (int nt = 0; nt < 4; ++nt) {
      const ushort* kr = &Kb[(size_t)(kt + nt * 16 + llo) * DH + lhi * 8];
      bf16x8 kb0 = *(const bf16x8*)kr;
      bf16x8 kb1 = *(const bf16x8*)(kr + 32);
      s[nt] = __builtin_amdgcn_mfma_f32_16x16x32_bf16(qa0, kb0, s[nt], 0, 0, 0);
      s[nt] = __builtin_amdgcn_mfma_f32_16x16x32_bf16(qa1, kb1, s[nt], 0, 0, 0);
    }

    // ---- mask (key = nt*16 + llo == C-layout column) ----
#pragma unroll
    for (int nt = 0; nt < 4; ++nt) {
      if (!mb[kt + nt * 16 + llo]) {
#pragma unroll
        for (int r = 0; r < 4; ++r) s[nt][r] = -INFINITY;
      }
    }

    // ---- online softmax; row r of lane = q-row lhi*4+r, spread over 16 lanes
    float p[4][4];
    float alpha[4];
#pragma unroll
    for (int r = 0; r < 4; ++r) {
      float tmax = fmaxf(fmaxf(s[0][r], s[1][r]), fmaxf(s[2][r], s[3][r]));
      tmax = fmaxf(tmax, __shfl_xor(tmax, 1));
      tmax = fmaxf(tmax, __shfl_xor(tmax, 2));
      tmax = fmaxf(tmax, __shfl_xor(tmax, 4));
      tmax = fmaxf(tmax, __shfl_xor(tmax, 8));
      float newm = fmaxf(mrow[r], tmax);
      float a, rsum;
      if (newm == -INFINITY) {  // all keys masked so far
        a = 1.f;
        rsum = 0.f;
#pragma unroll
        for (int nt = 0; nt < 4; ++nt) p[nt][r] = 0.f;
      } else {
        a = __expf(mrow[r] - newm);
        rsum = 0.f;
#pragma unroll
        for (int nt = 0; nt < 4; ++nt) {
          p[nt][r] = __expf(s[nt][r] - newm);
          rsum += p[nt][r];
        }
        rsum += __shfl_xor(rsum, 1);
        rsum += __shfl_xor(rsum, 2);
        rsum += __shfl_xor(rsum, 4);
        rsum += __shfl_xor(rsum, 8);
      }
      mrow[r] = newm;
      lrow[r] = lrow[r] * a + rsum;
      alpha[r] = a;
    }
#pragma unroll
    for (int nt = 0; nt < 4; ++nt) {
      oacc[nt][0] *= alpha[0];
      oacc[nt][1] *= alpha[1];
      oacc[nt][2] *= alpha[2];
      oacc[nt][3] *= alpha[3];
    }

    // ---- P (C-layout) -> per-wave LDS in A-layout source form ----
#pragma unroll
    for (int nt = 0; nt < 4; ++nt)
#pragma unroll
      for (int r = 0; r < 4; ++r)
        pl[(lhi * 4 + r) * 72 + nt * 16 + llo] = f2bf(p[nt][r]);

    // ---- O += P V ----
#pragma unroll
    for (int kc = 0; kc < 2; ++kc) {
      bf16x8 pa = *(const bf16x8*)&pl[llo * 72 + kc * 32 + lhi * 8];
#pragma unroll
      for (int nt = 0; nt < 4; ++nt) {
        bf16x8 vb = *(const bf16x8*)
            &Vb[(size_t)(nt * 16 + llo) * TB + kt + kc * 32 + lhi * 8];
        oacc[nt] = __builtin_amdgcn_mfma_f32_16x16x32_bf16(pa, vb, oacc[nt], 0, 0, 0);
      }
    }
  }

  // ---- epilogue: normalize, write context [B,T,D] fp32 ----
#pragma unroll
  for (int r = 0; r < 4; ++r) {
    float inv = lrow[r] > 0.f ? 1.f / lrow[r] : 0.f;
    int t = q0 + w * 16 + lhi * 4 + r;
    float* xr = &Xc[((size_t)b * TB + t) * DD + h * DH];
#pragma unroll
    for (int nt = 0; nt < 4; ++nt) xr[nt * 16 + llo] = oacc[nt][r] * inv;
  }
}

// ---------------------------------------------------------------------------
extern "C" void kernel_launch(void* const* d_in, const int* in_sizes, int n_in,
                              void* d_out, int out_size, void* d_ws,
                              size_t ws_size, hipStream_t stream) {
  (void)in_sizes; (void)n_in; (void)out_size; (void)ws_size;
  const float* q = (const float*)d_in[0];
  const float* k = (const float*)d_in[1];
  const float* v = (const float*)d_in[2];
  const void* pm = d_in[3];
  const float* Wq = (const float*)d_in[4];
  const float* bq = (const float*)d_in[5];
  const float* Wk = (const float*)d_in[6];
  const float* bk = (const float*)d_in[7];
  const float* Wv = (const float*)d_in[8];
  const float* bv = (const float*)d_in[9];
  const float* Wo = (const float*)d_in[10];
  const float* bo = (const float*)d_in[11];

  char* ws = (char*)d_ws;
  ushort* Qh = (ushort*)(ws);                          // 8 MiB
  ushort* Kh = (ushort*)(ws + ((size_t)8 << 20));      // 8 MiB
  ushort* Vt = (ushort*)(ws + ((size_t)16 << 20));     // 8 MiB
  float* Xc = (float*)(ws + ((size_t)24 << 20));       // 32 MiB
  int* maskc = (int*)(ws + ((size_t)56 << 20));        // 32 KiB
  int* mode = (int*)(ws + ((size_t)56 << 20) + 32768);

  mask_detect_kernel<<<1, 256, 0, stream>>>((const unsigned char*)pm, mode);
  mask_build_kernel<<<32, 256, 0, stream>>>(pm, mode, maskc);

  dim3 gg(DD / 128, (4 * TB) / 128);  // (4, 64)
  proj_gemm_kernel<0><<<gg, 256, 0, stream>>>(q, Wq, bq, Qh, 0.125f);
  proj_gemm_kernel<0><<<gg, 256, 0, stream>>>(k, Wk, bk, Kh, 1.0f);
  proj_gemm_kernel<2><<<gg, 256, 0, stream>>>(v, Wv, bv, Vt, 1.0f);

  attn_mfma_kernel<<<1024, 256, 0, stream>>>(Qh, Kh, Vt, maskc, Xc);

  proj_gemm_kernel<1><<<gg, 256, 0, stream>>>(Xc, Wo, bo, d_out, 1.0f);
}

// Round 3
// 440.348 us; speedup vs baseline: 2.0599x; 1.6001x over previous
//
#include <hip/hip_runtime.h>
#include <hip/hip_bf16.h>
#include <math.h>

// MultiHeadAttention  B=4, T=2048, D=512, H=8, DH=64, fp32 in/out.
// R3: Q/K/V projections on bf16 MFMA (LDS-free, fragments from L2);
// attention adds register double-buffering (K prefetch, V early-issue).
// O-projection stays exact fp32 VALU.

#define TB 2048
#define DD 512
#define NH 8
#define DH 64

typedef short bf16x8 __attribute__((ext_vector_type(8)));
typedef float f32x4 __attribute__((ext_vector_type(4)));
typedef ushort u16x8 __attribute__((ext_vector_type(8)));

static __device__ __forceinline__ ushort f2bf(float x) {
  __hip_bfloat16 h = __float2bfloat16(x);
  return *reinterpret_cast<ushort*>(&h);
}

// ---------------------------------------------------------------------------
// Mask canonicalization (verified in R1/R2).
__global__ void mask_detect_kernel(const unsigned char* __restrict__ m,
                                   int* __restrict__ mode) {
  __shared__ int c1, c2;
  if (threadIdx.x == 0) { c1 = 0; c2 = 0; }
  __syncthreads();
  int l1 = 0, l2 = 0;
  for (int i = threadIdx.x; i < 8192; i += blockDim.x) {
    int ph = i & 3;
    unsigned char v = m[i];
    if (ph == 1 && v) l1++;
    if (ph == 2 && v) l2++;
  }
  if (l1) atomicAdd(&c1, l1);
  if (l2) atomicAdd(&c2, l2);
  __syncthreads();
  if (threadIdx.x == 0) *mode = (c1 > 0) ? 0 : ((c2 > 0) ? 1 : 2);
}

__global__ void mask_build_kernel(const void* __restrict__ m,
                                  const int* __restrict__ mode,
                                  int* __restrict__ out) {
  int i = blockIdx.x * blockDim.x + threadIdx.x;
  int md = *mode;
  int v;
  if (md == 0)      v = ((const unsigned char*)m)[i] != 0;
  else if (md == 1) v = ((const float*)m)[i] != 0.0f;
  else              v = ((const int*)m)[i] != 0;
  out[i] = v;
}

// ---------------------------------------------------------------------------
// fp32 -> bf16 bulk convert (same layout). 8 elems/thread.
__global__ __launch_bounds__(256) void cvt_kernel(const float* __restrict__ in,
                                                  ushort* __restrict__ out) {
  size_t i = ((size_t)blockIdx.x * 256 + threadIdx.x) * 8;
  float4 a = *(const float4*)&in[i];
  float4 b = *(const float4*)&in[i + 4];
  u16x8 o;
  o[0] = f2bf(a.x); o[1] = f2bf(a.y); o[2] = f2bf(a.z); o[3] = f2bf(a.w);
  o[4] = f2bf(b.x); o[5] = f2bf(b.y); o[6] = f2bf(b.z); o[7] = f2bf(b.w);
  *(u16x8*)&out[i] = o;
}

// ---------------------------------------------------------------------------
// W [K][N] f32 -> Wt [N][K] bf16 (transpose via LDS tile).
__global__ __launch_bounds__(256) void wtrans_kernel(const float* __restrict__ W,
                                                     ushort* __restrict__ Wt) {
  __shared__ ushort t[64][68];
  const int bn = blockIdx.x << 6, bk = blockIdx.y << 6;
  const int tx = threadIdx.x & 15, ty = threadIdx.x >> 4;
#pragma unroll
  for (int rr = 0; rr < 64; rr += 16) {
    float4 v = *(const float4*)&W[(size_t)(bk + rr + ty) * DD + bn + (tx << 2)];
    t[(tx << 2) + 0][rr + ty] = f2bf(v.x);
    t[(tx << 2) + 1][rr + ty] = f2bf(v.y);
    t[(tx << 2) + 2][rr + ty] = f2bf(v.z);
    t[(tx << 2) + 3][rr + ty] = f2bf(v.w);
  }
  __syncthreads();
#pragma unroll
  for (int rr = 0; rr < 64; rr += 16) {
    ushort4 o;
    o.x = t[rr + ty][(tx << 2) + 0];
    o.y = t[rr + ty][(tx << 2) + 1];
    o.z = t[rr + ty][(tx << 2) + 2];
    o.w = t[rr + ty][(tx << 2) + 3];
    *(ushort4*)&Wt[(size_t)(bn + rr + ty) * DD + bk + (tx << 2)] = o;
  }
}

// ---------------------------------------------------------------------------
// bf16 MFMA projection GEMM: Y = (Xb @ Wt^T + b) * scale.
// One wave per block (64 thr); wave tile 32 rows x 64 cols; K=512 in 16 steps.
// No LDS: A/B fragments straight from global (B panels L2-resident).
// MODE 0: Y bf16 [B,H,T,DH]; MODE 2: Y bf16 [B,H,DH,T] (V transposed).
template <int MODE>
__global__ __launch_bounds__(64) void proj_mfma_kernel(
    const ushort* __restrict__ Xb,   // [8192][512] bf16
    const ushort* __restrict__ Wt,   // [512 n][512 k] bf16
    const float* __restrict__ bias,  // [512] f32
    ushort* __restrict__ Y, float scale) {
  const int lane = threadIdx.x;
  const int llo = lane & 15, lhi = lane >> 4;
  const int m0 = blockIdx.x << 5;  // 0..8160
  const int n0 = blockIdx.y << 6;  // 0..448

  f32x4 acc[2][4];
#pragma unroll
  for (int mi = 0; mi < 2; ++mi)
#pragma unroll
    for (int nt = 0; nt < 4; ++nt) acc[mi][nt] = (f32x4){0.f, 0.f, 0.f, 0.f};

  const ushort* Arow = Xb + (size_t)(m0 + llo) * DD;  // + mi*16*DD
  const ushort* Brow = Wt + (size_t)(n0 + llo) * DD;  // + nt*16*DD

#pragma unroll 4
  for (int ks = 0; ks < 16; ++ks) {
    const int ko = ks * 32 + lhi * 8;
    bf16x8 a0 = *(const bf16x8*)&Arow[ko];
    bf16x8 a1 = *(const bf16x8*)&Arow[16 * DD + ko];
    bf16x8 b0 = *(const bf16x8*)&Brow[ko];
    bf16x8 b1 = *(const bf16x8*)&Brow[16 * DD + ko];
    bf16x8 b2 = *(const bf16x8*)&Brow[32 * DD + ko];
    bf16x8 b3 = *(const bf16x8*)&Brow[48 * DD + ko];
    acc[0][0] = __builtin_amdgcn_mfma_f32_16x16x32_bf16(a0, b0, acc[0][0], 0, 0, 0);
    acc[0][1] = __builtin_amdgcn_mfma_f32_16x16x32_bf16(a0, b1, acc[0][1], 0, 0, 0);
    acc[0][2] = __builtin_amdgcn_mfma_f32_16x16x32_bf16(a0, b2, acc[0][2], 0, 0, 0);
    acc[0][3] = __builtin_amdgcn_mfma_f32_16x16x32_bf16(a0, b3, acc[0][3], 0, 0, 0);
    acc[1][0] = __builtin_amdgcn_mfma_f32_16x16x32_bf16(a1, b0, acc[1][0], 0, 0, 0);
    acc[1][1] = __builtin_amdgcn_mfma_f32_16x16x32_bf16(a1, b1, acc[1][1], 0, 0, 0);
    acc[1][2] = __builtin_amdgcn_mfma_f32_16x16x32_bf16(a1, b2, acc[1][2], 0, 0, 0);
    acc[1][3] = __builtin_amdgcn_mfma_f32_16x16x32_bf16(a1, b3, acc[1][3], 0, 0, 0);
  }

  // epilogue: C[row][col], row = m0+mi*16+lhi*4+r, col = n0+nt*16+llo
  const int b = m0 >> 11;        // blocks of 32 rows never straddle batch
  const int h = n0 >> 6;         // 64-col panel == one head
  float bb[4];
#pragma unroll
  for (int nt = 0; nt < 4; ++nt) bb[nt] = bias[n0 + nt * 16 + llo];

  if (MODE == 0) {
    ushort* Yb = Y + ((size_t)(b * NH + h) * TB) * DH;
#pragma unroll
    for (int mi = 0; mi < 2; ++mi)
#pragma unroll
      for (int nt = 0; nt < 4; ++nt) {
        int dh = nt * 16 + llo;
#pragma unroll
        for (int r = 0; r < 4; ++r) {
          int t = (m0 & (TB - 1)) + mi * 16 + lhi * 4 + r;
          Yb[(size_t)t * DH + dh] = f2bf((acc[mi][nt][r] + bb[nt]) * scale);
        }
      }
  } else {  // MODE 2: Vt[b][h][dh][t]
    ushort* Yb = Y + ((size_t)(b * NH + h) * DH) * TB;
#pragma unroll
    for (int mi = 0; mi < 2; ++mi) {
      int t0 = (m0 & (TB - 1)) + mi * 16 + lhi * 4;
#pragma unroll
      for (int nt = 0; nt < 4; ++nt) {
        int dh = nt * 16 + llo;
        ushort4 o;
        o.x = f2bf((acc[mi][nt][0] + bb[nt]) * scale);
        o.y = f2bf((acc[mi][nt][1] + bb[nt]) * scale);
        o.z = f2bf((acc[mi][nt][2] + bb[nt]) * scale);
        o.w = f2bf((acc[mi][nt][3] + bb[nt]) * scale);
        *(ushort4*)&Yb[(size_t)dh * TB + t0] = o;
      }
    }
  }
}

// ---------------------------------------------------------------------------
// bf16 MFMA flash attention with register double-buffering.
// 1024 blocks (XCD-swizzled: same-bh blocks share an XCD L2), 4 indep waves.
// Per 64-key tile: V+mask issued early (covered by QK^T+softmax); next K tile
// prefetched after QK^T (covered by softmax+PV).
__global__ __launch_bounds__(256) void attn_mfma_kernel(
    const ushort* __restrict__ Qh,  // [BH][T][DH], pre-scaled by 0.125
    const ushort* __restrict__ Kh,  // [BH][T][DH]
    const ushort* __restrict__ Vt,  // [BH][DH][T]
    const int* __restrict__ maskc,  // [B][T]
    float* __restrict__ Xc) {       // [B][T][D] f32
  __shared__ __align__(16) ushort Plds[4][16][72];

  const int tid = threadIdx.x;
  const int w = tid >> 6, lane = tid & 63;
  const int lhi = lane >> 4, llo = lane & 15;

  const int bid = blockIdx.x;
  const int j = bid >> 3;
  const int bh = (bid & 7) + ((j >> 5) << 3);
  const int qt = j & 31;
  const int b = bh >> 3, h = bh & 7;
  const int q0 = qt << 6;

  const ushort* Qb = Qh + ((size_t)bh * TB + q0 + w * 16) * DH;
  const ushort* Kb = Kh + (size_t)bh * TB * DH;
  const ushort* Vb = Vt + (size_t)bh * DH * TB;
  const int* mb = maskc + b * TB;
  ushort* pl = &Plds[w][0][0];

  bf16x8 qa0 = *(const bf16x8*)&Qb[llo * DH + lhi * 8];
  bf16x8 qa1 = *(const bf16x8*)&Qb[llo * DH + 32 + lhi * 8];

  f32x4 oacc[4];
  float mrow[4], lrow[4];
#pragma unroll
  for (int i = 0; i < 4; ++i) {
    oacc[i] = (f32x4){0.f, 0.f, 0.f, 0.f};
    mrow[i] = -INFINITY;
    lrow[i] = 0.f;
  }

  // K prologue: tile 0 fragments
  bf16x8 kf[4][2];
#pragma unroll
  for (int nt = 0; nt < 4; ++nt) {
    const ushort* kr = &Kb[(size_t)(nt * 16 + llo) * DH + lhi * 8];
    kf[nt][0] = *(const bf16x8*)kr;
    kf[nt][1] = *(const bf16x8*)(kr + 32);
  }

  for (int kt = 0; kt < TB; kt += 64) {
    // ---- early-issue V fragments + mask for THIS tile ----
    bf16x8 vf[2][4];
#pragma unroll
    for (int kc = 0; kc < 2; ++kc)
#pragma unroll
      for (int nt = 0; nt < 4; ++nt)
        vf[kc][nt] = *(const bf16x8*)
            &Vb[(size_t)(nt * 16 + llo) * TB + kt + kc * 32 + lhi * 8];
    int keep[4];
#pragma unroll
    for (int nt = 0; nt < 4; ++nt) keep[nt] = mb[kt + nt * 16 + llo];

    // ---- S = Q K^T (kf ready from prefetch) ----
    f32x4 s[4];
#pragma unroll
    for (int nt = 0; nt < 4; ++nt) {
      s[nt] = (f32x4){0.f, 0.f, 0.f, 0.f};
      s[nt] = __builtin_amdgcn_mfma_f32_16x16x32_bf16(qa0, kf[nt][0], s[nt], 0, 0, 0);
      s[nt] = __builtin_amdgcn_mfma_f32_16x16x32_bf16(qa1, kf[nt][1], s[nt], 0, 0, 0);
    }

    // ---- prefetch K for next tile (wraps at end; harmless valid loads) ----
    const int ktn = (kt + 64) & (TB - 1);
#pragma unroll
    for (int nt = 0; nt < 4; ++nt) {
      const ushort* kr = &Kb[(size_t)(ktn + nt * 16 + llo) * DH + lhi * 8];
      kf[nt][0] = *(const bf16x8*)kr;
      kf[nt][1] = *(const bf16x8*)(kr + 32);
    }

    // ---- mask ----
#pragma unroll
    for (int nt = 0; nt < 4; ++nt) {
      if (!keep[nt]) {
#pragma unroll
        for (int r = 0; r < 4; ++r) s[nt][r] = -INFINITY;
      }
    }

    // ---- online softmax (rows spread over 16 lanes) ----
    float p[4][4];
    float alpha[4];
#pragma unroll
    for (int r = 0; r < 4; ++r) {
      float tmax = fmaxf(fmaxf(s[0][r], s[1][r]), fmaxf(s[2][r], s[3][r]));
      tmax = fmaxf(tmax, __shfl_xor(tmax, 1));
      tmax = fmaxf(tmax, __shfl_xor(tmax, 2));
      tmax = fmaxf(tmax, __shfl_xor(tmax, 4));
      tmax = fmaxf(tmax, __shfl_xor(tmax, 8));
      float newm = fmaxf(mrow[r], tmax);
      float a, rsum;
      if (newm == -INFINITY) {
        a = 1.f;
        rsum = 0.f;
#pragma unroll
        for (int nt = 0; nt < 4; ++nt) p[nt][r] = 0.f;
      } else {
        a = __expf(mrow[r] - newm);
        rsum = 0.f;
#pragma unroll
        for (int nt = 0; nt < 4; ++nt) {
          p[nt][r] = __expf(s[nt][r] - newm);
          rsum += p[nt][r];
        }
        rsum += __shfl_xor(rsum, 1);
        rsum += __shfl_xor(rsum, 2);
        rsum += __shfl_xor(rsum, 4);
        rsum += __shfl_xor(rsum, 8);
      }
      mrow[r] = newm;
      lrow[r] = lrow[r] * a + rsum;
      alpha[r] = a;
    }
#pragma unroll
    for (int nt = 0; nt < 4; ++nt) {
      oacc[nt][0] *= alpha[0];
      oacc[nt][1] *= alpha[1];
      oacc[nt][2] *= alpha[2];
      oacc[nt][3] *= alpha[3];
    }

    // ---- P (C-layout) -> per-wave LDS (A-layout source) ----
#pragma unroll
    for (int nt = 0; nt < 4; ++nt)
#pragma unroll
      for (int r = 0; r < 4; ++r)
        pl[(lhi * 4 + r) * 72 + nt * 16 + llo] = f2bf(p[nt][r]);

    // ---- O += P V (vf issued ~400 cycles ago) ----
#pragma unroll
    for (int kc = 0; kc < 2; ++kc) {
      bf16x8 pa = *(const bf16x8*)&pl[llo * 72 + kc * 32 + lhi * 8];
#pragma unroll
      for (int nt = 0; nt < 4; ++nt)
        oacc[nt] = __builtin_amdgcn_mfma_f32_16x16x32_bf16(pa, vf[kc][nt], oacc[nt], 0, 0, 0);
    }
  }

  // ---- epilogue ----
#pragma unroll
  for (int r = 0; r < 4; ++r) {
    float inv = lrow[r] > 0.f ? 1.f / lrow[r] : 0.f;
    int t = q0 + w * 16 + lhi * 4 + r;
    float* xr = &Xc[((size_t)b * TB + t) * DD + h * DH];
#pragma unroll
    for (int nt = 0; nt < 4; ++nt) xr[nt * 16 + llo] = oacc[nt][r] * inv;
  }
}

// ---------------------------------------------------------------------------
// Exact fp32 GEMM for the O-projection (verified R1 structure, MODE-1 only).
__global__ __launch_bounds__(256) void oproj_kernel(
    const float* __restrict__ A, const float* __restrict__ W,
    const float* __restrict__ bias, float* __restrict__ Y) {
  __shared__ float As[16][128];
  __shared__ float Bs[16][128];

  const int tid = threadIdx.x;
  const int tx = tid & 15, ty = tid >> 4;
  const int bm = blockIdx.y << 7;
  const int bn = blockIdx.x << 7;

  float acc[8][8];
#pragma unroll
  for (int i = 0; i < 8; ++i)
#pragma unroll
    for (int j = 0; j < 8; ++j) acc[i][j] = 0.f;

  for (int k0 = 0; k0 < DD; k0 += 16) {
    float4 av[2], bv[2];
#pragma unroll
    for (int l = 0; l < 2; ++l) {
      int f = tid + l * 256;
      av[l] = *(const float4*)&A[(size_t)(bm + (f >> 2)) * DD + k0 + ((f & 3) << 2)];
      bv[l] = *(const float4*)&W[(size_t)(k0 + (f >> 5)) * DD + bn + ((f & 31) << 2)];
    }
    __syncthreads();
#pragma unroll
    for (int l = 0; l < 2; ++l) {
      int f = tid + l * 256;
      int r = f >> 2, c4 = (f & 3) << 2;
      As[c4 + 0][r] = av[l].x;
      As[c4 + 1][r] = av[l].y;
      As[c4 + 2][r] = av[l].z;
      As[c4 + 3][r] = av[l].w;
      *(float4*)&Bs[f >> 5][(f & 31) << 2] = bv[l];
    }
    __syncthreads();
#pragma unroll 8
    for (int kk = 0; kk < 16; ++kk) {
      float4 a0 = *(const float4*)&As[kk][ty << 2];
      float4 a1 = *(const float4*)&As[kk][(ty << 2) + 64];
      float4 b0 = *(const float4*)&Bs[kk][tx << 2];
      float4 b1 = *(const float4*)&Bs[kk][(tx << 2) + 64];
      float ar[8] = {a0.x, a0.y, a0.z, a0.w, a1.x, a1.y, a1.z, a1.w};
      float br[8] = {b0.x, b0.y, b0.z, b0.w, b1.x, b1.y, b1.z, b1.w};
#pragma unroll
      for (int i = 0; i < 8; ++i)
#pragma unroll
        for (int j = 0; j < 8; ++j) acc[i][j] += ar[i] * br[j];
    }
    __syncthreads();
  }

#pragma unroll
  for (int rg = 0; rg < 2; ++rg)
#pragma unroll
    for (int i = 0; i < 4; ++i) {
      int row = bm + rg * 64 + (ty << 2) + i;
#pragma unroll
      for (int cg = 0; cg < 2; ++cg) {
        int col = bn + cg * 64 + (tx << 2);
        float4 bb = *(const float4*)&bias[col];
        float4 o;
        o.x = acc[rg * 4 + i][cg * 4 + 0] + bb.x;
        o.y = acc[rg * 4 + i][cg * 4 + 1] + bb.y;
        o.z = acc[rg * 4 + i][cg * 4 + 2] + bb.z;
        o.w = acc[rg * 4 + i][cg * 4 + 3] + bb.w;
        *(float4*)&Y[(size_t)row * DD + col] = o;
      }
    }
}

// ---------------------------------------------------------------------------
extern "C" void kernel_launch(void* const* d_in, const int* in_sizes, int n_in,
                              void* d_out, int out_size, void* d_ws,
                              size_t ws_size, hipStream_t stream) {
  (void)in_sizes; (void)n_in; (void)out_size; (void)ws_size;
  const float* q = (const float*)d_in[0];
  const float* k = (const float*)d_in[1];
  const float* v = (const float*)d_in[2];
  const void* pm = d_in[3];
  const float* Wq = (const float*)d_in[4];
  const float* bq = (const float*)d_in[5];
  const float* Wk = (const float*)d_in[6];
  const float* bk = (const float*)d_in[7];
  const float* Wv = (const float*)d_in[8];
  const float* bv = (const float*)d_in[9];
  const float* Wo = (const float*)d_in[10];
  const float* bo = (const float*)d_in[11];

  char* ws = (char*)d_ws;
  const size_t MB = (size_t)1 << 20;
  // Region A [0,32MB): bf16 inputs + transposed weights (dead after projs);
  // Xc (32MB f32) aliases it after attention reads only Qh/Kh/Vt.
  ushort* Qb16 = (ushort*)(ws);
  ushort* Kb16 = (ushort*)(ws + 8 * MB);
  ushort* Vb16 = (ushort*)(ws + 16 * MB);
  ushort* Wqt = (ushort*)(ws + 24 * MB);
  ushort* Wkt = (ushort*)(ws + 24 * MB + 512 * 1024);
  ushort* Wvt = (ushort*)(ws + 25 * MB);
  float* Xc = (float*)(ws);  // 32MB, overlaps region A (safe: after projs)
  // Region B [32MB,56MB): projected heads (live through attention)
  ushort* Qh = (ushort*)(ws + 32 * MB);
  ushort* Kh = (ushort*)(ws + 40 * MB);
  ushort* Vt = (ushort*)(ws + 48 * MB);
  int* maskc = (int*)(ws + 56 * MB);
  int* mode = (int*)(ws + 56 * MB + 32768);

  mask_detect_kernel<<<1, 256, 0, stream>>>((const unsigned char*)pm, mode);
  mask_build_kernel<<<32, 256, 0, stream>>>(pm, mode, maskc);

  cvt_kernel<<<2048, 256, 0, stream>>>(q, Qb16);
  cvt_kernel<<<2048, 256, 0, stream>>>(k, Kb16);
  cvt_kernel<<<2048, 256, 0, stream>>>(v, Vb16);
  wtrans_kernel<<<dim3(8, 8), 256, 0, stream>>>(Wq, Wqt);
  wtrans_kernel<<<dim3(8, 8), 256, 0, stream>>>(Wk, Wkt);
  wtrans_kernel<<<dim3(8, 8), 256, 0, stream>>>(Wv, Wvt);

  dim3 pg(256, 8);  // 2048 one-wave blocks
  proj_mfma_kernel<0><<<pg, 64, 0, stream>>>(Qb16, Wqt, bq, Qh, 0.125f);
  proj_mfma_kernel<0><<<pg, 64, 0, stream>>>(Kb16, Wkt, bk, Kh, 1.0f);
  proj_mfma_kernel<2><<<pg, 64, 0, stream>>>(Vb16, Wvt, bv, Vt, 1.0f);

  attn_mfma_kernel<<<1024, 256, 0, stream>>>(Qh, Kh, Vt, maskc, Xc);

  oproj_kernel<<<dim3(4, 64), 256, 0, stream>>>(Xc, Wo, bo, (float*)d_out);
}